// Round 8
// baseline (403.291 us; speedup 1.0000x reference)
//
#include <hip/hip_runtime.h>
#include <stdint.h>

#define BATCH 2
#define SEQ   2048
#define DIM   1024
#define NH    16
#define DH    64

typedef short bf16x8 __attribute__((ext_vector_type(8)));
typedef float floatx4 __attribute__((ext_vector_type(4)));

__device__ __forceinline__ int swz(int r) { return (r ^ (r >> 2)) & 3; }

// Split two fp32 into packed bf16 hi-pair and lo-pair (truncation split)
__device__ __forceinline__ void split2(float x0, float x1, uint32_t& hi, uint32_t& lo) {
    uint32_t u0 = __float_as_uint(x0), u1 = __float_as_uint(x1);
    uint32_t m0 = u0 & 0xFFFF0000u;
    uint32_t m1 = u1 & 0xFFFF0000u;
    hi = (u0 >> 16) | m1;
    float l0 = x0 - __uint_as_float(m0);
    float l1 = x1 - __uint_as_float(m1);
    lo = (__float_as_uint(l0) >> 16) | (__float_as_uint(l1) & 0xFFFF0000u);
}

__device__ __forceinline__ uint32_t pack_bf16_rne(float x0, float x1) {
    uint32_t u0 = __float_as_uint(x0), u1 = __float_as_uint(x1);
    u0 += 0x7FFFu + ((u0 >> 16) & 1);
    u1 += 0x7FFFu + ((u1 >> 16) & 1);
    return (u0 >> 16) | (u1 & 0xFFFF0000u);
}

// ---------------- bf16x3 MFMA GEMM, 128x128 tile ----------------------------
// AMODE 0: fp32 A [M][1024], in-kernel split (R2-verified staging+swizzle).
// AMODE 1: pre-split A h/l [M][512 words], uint4-load + ds_write (R4-verified).
// B: fp32 [K][N], in-kernel split+transpose+swizzle (R2-verified).
// EPI: 0 = fp32+bias -> Cf; 1 = qv (cols<1024 split -> O1h/O1l, else bf16 -> O2);
//      2 = split -> O1h/O1l.  K=1024 fixed.
template<int AMODE, int EPI>
__global__ __launch_bounds__(256, 3)
void gemm_x3(const float* __restrict__ Af,
             const uint32_t* __restrict__ Ahg, const uint32_t* __restrict__ Alg,
             const float* __restrict__ Bf, const float* __restrict__ bias,
             float* __restrict__ Cf,
             uint32_t* __restrict__ O1h, uint32_t* __restrict__ O1l,
             uint32_t* __restrict__ O2, int N)
{
    __shared__ uint32_t Ah[128 * 16], Al[128 * 16], Bh[128 * 16], Bl[128 * 16];

    const int t    = threadIdx.x;
    const int lane = t & 63;
    const int w    = t >> 6;
    const int wm   = w & 1, wn = w >> 1;
    const int quad = lane >> 4, l15 = lane & 15;
    const int m0 = blockIdx.y * 128, n0 = blockIdx.x * 128;

    // fp32-A staging coords (R2)
    const int ar  = t >> 1;
    const int ab0 = (t & 1) * 2;
    const int as  = swz(ar);
    // fp32-B staging coords (R2)
    const int bc  = (t & 31) * 4;
    const int bk  = (t >> 5) * 4;
    const int bb  = bk >> 3;
    const int bp  = (bk & 7) >> 1;

    floatx4 acc[4][4];
    #pragma unroll
    for (int i = 0; i < 4; i++)
        #pragma unroll
        for (int j = 0; j < 4; j++)
            #pragma unroll
            for (int e = 0; e < 4; e++) acc[i][j][e] = 0.0f;

    for (int k0 = 0; k0 < 1024; k0 += 32) {
        if (k0) __syncthreads();
        // ---- stage A ----
        if constexpr (AMODE == 0) {
            float f[16];
            #pragma unroll
            for (int i = 0; i < 4; i++)
                *(float4*)&f[i * 4] =
                    *(const float4*)&Af[(size_t)(m0 + ar) * 1024 + k0 + ab0 * 8 + i * 4];
            uint32_t hi[8], lo[8];
            #pragma unroll
            for (int j = 0; j < 8; j++) split2(f[2 * j], f[2 * j + 1], hi[j], lo[j]);
            int i0 = ar * 16 + ((ab0 ^ as) * 4);
            int i1 = ar * 16 + (((ab0 + 1) ^ as) * 4);
            *(uint4*)&Ah[i0] = make_uint4(hi[0], hi[1], hi[2], hi[3]);
            *(uint4*)&Ah[i1] = make_uint4(hi[4], hi[5], hi[6], hi[7]);
            *(uint4*)&Al[i0] = make_uint4(lo[0], lo[1], lo[2], lo[3]);
            *(uint4*)&Al[i1] = make_uint4(lo[4], lo[5], lo[6], lo[7]);
        } else {
            // R4-verified pre-split staging: uint4 loads + swizzled ds_write
            #pragma unroll
            for (int i = 0; i < 2; i++) {
                int idx = t + i * 256;
                int row = idx >> 2, kb = idx & 3;
                size_t src = (size_t)(m0 + row) * 512 + (k0 >> 1) + kb * 4;
                int dst = row * 16 + ((kb ^ swz(row)) * 4);
                *(uint4*)&Ah[dst] = *(const uint4*)&Ahg[src];
                *(uint4*)&Al[dst] = *(const uint4*)&Alg[src];
            }
        }
        // ---- stage B: fp32 -> split + transpose to [n][16w], swizzled ----
        {
            float4 g4[4];
            #pragma unroll
            for (int j = 0; j < 4; j++)
                g4[j] = *(const float4*)&Bf[(size_t)(k0 + bk + j) * N + n0 + bc];
            #pragma unroll
            for (int nn = 0; nn < 4; nn++) {
                int n = bc + nn;
                float e0 = ((const float*)&g4[0])[nn];
                float e1 = ((const float*)&g4[1])[nn];
                float e2 = ((const float*)&g4[2])[nn];
                float e3 = ((const float*)&g4[3])[nn];
                uint32_t h0, q0, h1, q1;
                split2(e0, e1, h0, q0);
                split2(e2, e3, h1, q1);
                int bi = n * 16 + ((bb ^ swz(n)) * 4) + bp;
                *(uint2*)&Bh[bi] = make_uint2(h0, h1);
                *(uint2*)&Bl[bi] = make_uint2(q0, q1);
            }
        }
        __syncthreads();

        // ---- fragments + swapped MFMA (lane l15 = C-row) ----
        bf16x8 vbh[4], vbl[4];
        #pragma unroll
        for (int fn = 0; fn < 4; fn++) {
            int br = wn * 64 + fn * 16 + l15;
            int bi = br * 16 + ((quad ^ swz(br)) * 4);
            vbh[fn] = *(const bf16x8*)&Bh[bi];
            vbl[fn] = *(const bf16x8*)&Bl[bi];
        }
        #pragma unroll
        for (int fm = 0; fm < 4; fm++) {
            int arow = wm * 64 + fm * 16 + l15;
            int ai = arow * 16 + ((quad ^ swz(arow)) * 4);
            bf16x8 vah = *(const bf16x8*)&Ah[ai];
            bf16x8 val = *(const bf16x8*)&Al[ai];
            #pragma unroll
            for (int fn = 0; fn < 4; fn++) {
                acc[fm][fn] = __builtin_amdgcn_mfma_f32_16x16x32_bf16(vbh[fn], vah, acc[fm][fn], 0, 0, 0);
                acc[fm][fn] = __builtin_amdgcn_mfma_f32_16x16x32_bf16(vbl[fn], vah, acc[fm][fn], 0, 0, 0);
                acc[fm][fn] = __builtin_amdgcn_mfma_f32_16x16x32_bf16(vbh[fn], val, acc[fm][fn], 0, 0, 0);
            }
        }
    }

    // ---- epilogue: row-contiguous stores (R4-verified) ----
    #pragma unroll
    for (int fm = 0; fm < 4; fm++) {
        int row = m0 + wm * 64 + fm * 16 + l15;
        #pragma unroll
        for (int fn = 0; fn < 4; fn++) {
            int colb = n0 + wn * 64 + fn * 16 + quad * 4;
            floatx4 a = acc[fm][fn];
            if constexpr (EPI == 0) {
                float4 bb4 = *(const float4*)&bias[colb];
                float4 v;
                v.x = a[0] + bb4.x; v.y = a[1] + bb4.y;
                v.z = a[2] + bb4.z; v.w = a[3] + bb4.w;
                *(float4*)&Cf[(size_t)row * N + colb] = v;
            } else if constexpr (EPI == 1) {
                if (colb < 1024) {
                    uint32_t h0, l0, h1, l1;
                    split2(a[0], a[1], h0, l0);
                    split2(a[2], a[3], h1, l1);
                    size_t wi = (size_t)row * 512 + (colb >> 1);
                    *(uint2*)&O1h[wi] = make_uint2(h0, h1);
                    *(uint2*)&O1l[wi] = make_uint2(l0, l1);
                } else {
                    uint32_t w0 = pack_bf16_rne(a[0], a[1]);
                    uint32_t w1 = pack_bf16_rne(a[2], a[3]);
                    *(uint2*)&O2[(size_t)row * 512 + ((colb - 1024) >> 1)] = make_uint2(w0, w1);
                }
            } else {
                uint32_t h0, l0, h1, l1;
                split2(a[0], a[1], h0, l0);
                split2(a[2], a[3], h1, l1);
                size_t wi = (size_t)row * 512 + (colb >> 1);
                *(uint2*)&O1h[wi] = make_uint2(h0, h1);
                *(uint2*)&O1l[wi] = make_uint2(l0, l1);
            }
        }
    }
}

// ---------------- MFMA flash attention, Br=128, Bc=64 (exact R5 kernel) -----
#define FST 34
__global__ __launch_bounds__(256, 2)
void flash_attn(const uint32_t* __restrict__ qhg, const uint32_t* __restrict__ qlg,
                const uint32_t* __restrict__ khg, const uint32_t* __restrict__ klg,
                const uint32_t* __restrict__ vbg,
                uint32_t* __restrict__ xhg, uint32_t* __restrict__ xlg)
{
    __shared__ uint32_t Qh[128 * FST], Ql[128 * FST];
    __shared__ uint32_t Kh[64 * FST],  Kl[64 * FST];
    __shared__ uint32_t Vt[64 * FST];
    __shared__ uint32_t Pt[128 * FST];

    const int t    = threadIdx.x;
    const int lane = t & 63;
    const int w    = t >> 6;
    const int quad = lane >> 4, l15 = lane & 15;
    const int qb = blockIdx.x;
    const int h  = blockIdx.y;
    const int b  = blockIdx.z;
    const float scale = 0.125f;

    const size_t rowbase = (size_t)b * SEQ;

    // ---- stage Q tile once: 128 rows x 32 words, h+l ----
    {
        int row = t >> 1, c0 = (t & 1) * 16;
        size_t gw = (rowbase + qb * 128 + row) * 512 + h * 32 + c0;
        #pragma unroll
        for (int j = 0; j < 4; j++) {
            *(uint4*)&Qh[row * FST + c0 + j * 4] = *(const uint4*)&qhg[gw + j * 4];
            *(uint4*)&Ql[row * FST + c0 + j * 4] = *(const uint4*)&qlg[gw + j * 4];
        }
    }

    float m_i[2] = {-INFINITY, -INFINITY};
    float l_i[2] = {0.0f, 0.0f};
    floatx4 acc_o[2][4];
    #pragma unroll
    for (int nf = 0; nf < 2; nf++)
        #pragma unroll
        for (int fm = 0; fm < 4; fm++)
            #pragma unroll
            for (int e = 0; e < 4; e++) acc_o[nf][fm][e] = 0.0f;

    for (int kt = 0; kt < SEQ / 64; kt++) {
        __syncthreads();
        // ---- stage K tile: 64 rows x 32 words, h+l ----
        {
            int row = t >> 2, c0 = (t & 3) * 8;
            size_t gw = (rowbase + kt * 64 + row) * 512 + h * 32 + c0;
            *(uint4*)&Kh[row * FST + c0]     = *(const uint4*)&khg[gw];
            *(uint4*)&Kh[row * FST + c0 + 4] = *(const uint4*)&khg[gw + 4];
            *(uint4*)&Kl[row * FST + c0]     = *(const uint4*)&klg[gw];
            *(uint4*)&Kl[row * FST + c0 + 4] = *(const uint4*)&klg[gw + 4];
        }
        // ---- stage V transposed: Vt[d][key] ----
        {
            int key0 = (t & 15) * 4, d0 = (t >> 4) * 4;
            uint2 v0 = *(const uint2*)&vbg[(rowbase + kt * 64 + key0 + 0) * 512 + h * 32 + (d0 >> 1)];
            uint2 v1 = *(const uint2*)&vbg[(rowbase + kt * 64 + key0 + 1) * 512 + h * 32 + (d0 >> 1)];
            uint2 v2 = *(const uint2*)&vbg[(rowbase + kt * 64 + key0 + 2) * 512 + h * 32 + (d0 >> 1)];
            uint2 v3 = *(const uint2*)&vbg[(rowbase + kt * 64 + key0 + 3) * 512 + h * 32 + (d0 >> 1)];
            uint32_t lo, hi;
            lo = (v0.x & 0xFFFFu) | (v1.x << 16);
            hi = (v2.x & 0xFFFFu) | (v3.x << 16);
            *(uint2*)&Vt[(d0 + 0) * FST + (key0 >> 1)] = make_uint2(lo, hi);
            lo = (v0.x >> 16) | (v1.x & 0xFFFF0000u);
            hi = (v2.x >> 16) | (v3.x & 0xFFFF0000u);
            *(uint2*)&Vt[(d0 + 1) * FST + (key0 >> 1)] = make_uint2(lo, hi);
            lo = (v0.y & 0xFFFFu) | (v1.y << 16);
            hi = (v2.y & 0xFFFFu) | (v3.y << 16);
            *(uint2*)&Vt[(d0 + 2) * FST + (key0 >> 1)] = make_uint2(lo, hi);
            lo = (v0.y >> 16) | (v1.y & 0xFFFF0000u);
            hi = (v2.y >> 16) | (v3.y & 0xFFFF0000u);
            *(uint2*)&Vt[(d0 + 3) * FST + (key0 >> 1)] = make_uint2(lo, hi);
        }
        __syncthreads();

        // ---- S^T = K·Q^T (bf16x3), 2 n-frags per wave ----
        floatx4 sacc[2][4];
        #pragma unroll
        for (int nf = 0; nf < 2; nf++)
            #pragma unroll
            for (int fm = 0; fm < 4; fm++)
                #pragma unroll
                for (int e = 0; e < 4; e++) sacc[nf][fm][e] = 0.0f;

        #pragma unroll
        for (int s = 0; s < 2; s++) {
            bf16x8 vqh[2], vql[2];
            #pragma unroll
            for (int nf = 0; nf < 2; nf++) {
                int qi = (w * 32 + nf * 16 + l15) * FST + s * 16 + quad * 4;
                vqh[nf] = *(const bf16x8*)&Qh[qi];
                vql[nf] = *(const bf16x8*)&Ql[qi];
            }
            #pragma unroll
            for (int fm = 0; fm < 4; fm++) {
                int ki = (fm * 16 + l15) * FST + s * 16 + quad * 4;
                bf16x8 vkh = *(const bf16x8*)&Kh[ki];
                bf16x8 vkl = *(const bf16x8*)&Kl[ki];
                #pragma unroll
                for (int nf = 0; nf < 2; nf++) {
                    sacc[nf][fm] = __builtin_amdgcn_mfma_f32_16x16x32_bf16(vkh, vqh[nf], sacc[nf][fm], 0, 0, 0);
                    sacc[nf][fm] = __builtin_amdgcn_mfma_f32_16x16x32_bf16(vkh, vql[nf], sacc[nf][fm], 0, 0, 0);
                    sacc[nf][fm] = __builtin_amdgcn_mfma_f32_16x16x32_bf16(vkl, vqh[nf], sacc[nf][fm], 0, 0, 0);
                }
            }
        }

        // ---- online softmax per (lane, nf) ----
        #pragma unroll
        for (int nf = 0; nf < 2; nf++) {
            float p[4][4];
            float mt = -INFINITY;
            #pragma unroll
            for (int fm = 0; fm < 4; fm++)
                #pragma unroll
                for (int r = 0; r < 4; r++) {
                    p[fm][r] = sacc[nf][fm][r] * scale;
                    mt = fmaxf(mt, p[fm][r]);
                }
            mt = fmaxf(mt, __shfl_xor(mt, 16));
            mt = fmaxf(mt, __shfl_xor(mt, 32));
            float m_new = fmaxf(m_i[nf], mt);
            float alpha = __expf(m_i[nf] - m_new);
            float rs = 0.0f;
            #pragma unroll
            for (int fm = 0; fm < 4; fm++)
                #pragma unroll
                for (int r = 0; r < 4; r++) {
                    p[fm][r] = __expf(p[fm][r] - m_new);
                    rs += p[fm][r];
                }
            rs += __shfl_xor(rs, 16);
            rs += __shfl_xor(rs, 32);
            l_i[nf] = l_i[nf] * alpha + rs;
            m_i[nf] = m_new;
            #pragma unroll
            for (int fm = 0; fm < 4; fm++)
                #pragma unroll
                for (int e = 0; e < 4; e++) acc_o[nf][fm][e] *= alpha;

            int qrow = w * 32 + nf * 16 + l15;
            #pragma unroll
            for (int fm = 0; fm < 4; fm++) {
                uint32_t u0 = pack_bf16_rne(p[fm][0], p[fm][1]);
                uint32_t u1 = pack_bf16_rne(p[fm][2], p[fm][3]);
                *(uint2*)&Pt[qrow * FST + fm * 8 + quad * 2] = make_uint2(u0, u1);
            }
        }

        // ---- O^T += Vt · P^T ----
        #pragma unroll
        for (int s = 0; s < 2; s++) {
            bf16x8 pb[2];
            #pragma unroll
            for (int nf = 0; nf < 2; nf++)
                pb[nf] = *(const bf16x8*)&Pt[(w * 32 + nf * 16 + l15) * FST + s * 16 + quad * 4];
            #pragma unroll
            for (int fm = 0; fm < 4; fm++) {
                bf16x8 va = *(const bf16x8*)&Vt[(fm * 16 + l15) * FST + s * 16 + quad * 4];
                #pragma unroll
                for (int nf = 0; nf < 2; nf++)
                    acc_o[nf][fm] = __builtin_amdgcn_mfma_f32_16x16x32_bf16(va, pb[nf], acc_o[nf][fm], 0, 0, 0);
            }
        }
    }

    // ---- epilogue: write x pre-split bf16 ----
    #pragma unroll
    for (int nf = 0; nf < 2; nf++) {
        float rl = 1.0f / l_i[nf];
        size_t row = rowbase + qb * 128 + w * 32 + nf * 16 + l15;
        #pragma unroll
        for (int fm = 0; fm < 4; fm++) {
            int d0 = fm * 16 + quad * 4;
            uint32_t h0, l0, h1, l1;
            split2(acc_o[nf][fm][0] * rl, acc_o[nf][fm][1] * rl, h0, l0);
            split2(acc_o[nf][fm][2] * rl, acc_o[nf][fm][3] * rl, h1, l1);
            size_t wi = row * 512 + ((h * 64 + d0) >> 1);
            *(uint2*)&xhg[wi] = make_uint2(h0, h1);
            *(uint2*)&xlg[wi] = make_uint2(l0, l1);
        }
    }
}

extern "C" void kernel_launch(void* const* d_in, const int* in_sizes, int n_in,
                              void* d_out, int out_size, void* d_ws, size_t ws_size,
                              hipStream_t stream)
{
    const float* input_qv = (const float*)d_in[0];
    const float* input_k  = (const float*)d_in[1];
    const float* W_qv     = (const float*)d_in[2];
    const float* W_k      = (const float*)d_in[3];
    const float* W_proj   = (const float*)d_in[4];
    const float* b_proj   = (const float*)d_in[5];
    float* out = (float*)d_out;

    const size_t RW = 4096 * 512;            // words per [4096][1024-bf16] buffer
    uint32_t* qh = (uint32_t*)d_ws;          // 5 RW = 41.9 MB total
    uint32_t* ql = qh + RW;
    uint32_t* vb = ql + RW;
    uint32_t* xh = vb + RW;
    uint32_t* xl = xh + RW;
    uint32_t* kh = (uint32_t*)d_out;         // split K parked in d_out (16.8 MB);
    uint32_t* kl = kh + RW;                  // proj GEMM rewrites out afterwards

    dim3 blk(256);
    // k projection: fp32 in-kernel split both operands
    gemm_x3<0, 2><<<dim3(8, 32), blk, 0, stream>>>(
        input_k, nullptr, nullptr, W_k, nullptr, nullptr, kh, kl, nullptr, 1024);
    // qv projection
    gemm_x3<0, 1><<<dim3(16, 32), blk, 0, stream>>>(
        input_qv, nullptr, nullptr, W_qv, nullptr, nullptr, qh, ql, vb, 2048);
    // flash attention (exact R5 kernel)
    flash_attn<<<dim3(SEQ / 128, NH, BATCH), blk, 0, stream>>>(
        qh, ql, kh, kl, vb, xh, xl);
    // output projection + bias: A = pre-split x, uint4-load staging (no DMA)
    gemm_x3<1, 0><<<dim3(8, 32), blk, 0, stream>>>(
        nullptr, xh, xl, W_proj, b_proj, out, nullptr, nullptr, nullptr, 1024);
}

// Round 9
// 336.828 us; speedup vs baseline: 1.1973x; 1.1973x over previous
//
#include <hip/hip_runtime.h>
#include <stdint.h>

#define BATCH 2
#define SEQ   2048
#define DIM   1024
#define NH    16
#define DH    64

typedef short bf16x8 __attribute__((ext_vector_type(8)));
typedef float floatx4 __attribute__((ext_vector_type(4)));

__device__ __forceinline__ int swz(int r) { return (r ^ (r >> 2)) & 3; }

// Split two fp32 into packed bf16 hi-pair and lo-pair (truncation split)
__device__ __forceinline__ void split2(float x0, float x1, uint32_t& hi, uint32_t& lo) {
    uint32_t u0 = __float_as_uint(x0), u1 = __float_as_uint(x1);
    uint32_t m0 = u0 & 0xFFFF0000u;
    uint32_t m1 = u1 & 0xFFFF0000u;
    hi = (u0 >> 16) | m1;
    float l0 = x0 - __uint_as_float(m0);
    float l1 = x1 - __uint_as_float(m1);
    lo = (__float_as_uint(l0) >> 16) | (__float_as_uint(l1) & 0xFFFF0000u);
}

__device__ __forceinline__ uint32_t pack_bf16_rne(float x0, float x1) {
    uint32_t u0 = __float_as_uint(x0), u1 = __float_as_uint(x1);
    u0 += 0x7FFFu + ((u0 >> 16) & 1);
    u1 += 0x7FFFu + ((u1 >> 16) & 1);
    return (u0 >> 16) | (u1 & 0xFFFF0000u);
}

// ---------------- fused qv+k projection GEMM, 128x128 tiles -----------------
// grid (24, 32): bx<16 -> qv (A=input_qv, B=W_qv, N=2048, split+bf16 out),
//                bx>=16 -> k (A=input_k, B=W_k, N=1024, split out).
// 768 blocks = exactly 3 blocks/CU. All staging paths R2/R8-verified.
__global__ __launch_bounds__(256, 3)
void gemm_qvk(const float* __restrict__ Aqv, const float* __restrict__ Akp,
              const float* __restrict__ Wqv, const float* __restrict__ Wkp,
              uint32_t* __restrict__ qh, uint32_t* __restrict__ ql,
              uint32_t* __restrict__ vb,
              uint32_t* __restrict__ kh, uint32_t* __restrict__ kl)
{
    __shared__ uint32_t Ah[128 * 16], Al[128 * 16], Bh[128 * 16], Bl[128 * 16];

    const int t    = threadIdx.x;
    const int lane = t & 63;
    const int w    = t >> 6;
    const int wm   = w & 1, wn = w >> 1;
    const int quad = lane >> 4, l15 = lane & 15;
    const int bx   = blockIdx.x;
    const bool is_qv = (bx < 16);
    const float* Af = is_qv ? Aqv : Akp;
    const float* Bf = is_qv ? Wqv : Wkp;
    const int N    = is_qv ? 2048 : 1024;
    const int n0   = (is_qv ? bx : bx - 16) * 128;
    const int m0   = blockIdx.y * 128;

    // fp32-A staging coords (R2)
    const int ar  = t >> 1;
    const int ab0 = (t & 1) * 2;
    const int as  = swz(ar);
    // fp32-B staging coords (R2)
    const int bc  = (t & 31) * 4;
    const int bk  = (t >> 5) * 4;
    const int bb  = bk >> 3;
    const int bp  = (bk & 7) >> 1;

    floatx4 acc[4][4];
    #pragma unroll
    for (int i = 0; i < 4; i++)
        #pragma unroll
        for (int j = 0; j < 4; j++)
            #pragma unroll
            for (int e = 0; e < 4; e++) acc[i][j][e] = 0.0f;

    for (int k0 = 0; k0 < 1024; k0 += 32) {
        if (k0) __syncthreads();
        // ---- stage A: fp32 -> split, swizzled (R2) ----
        {
            float f[16];
            #pragma unroll
            for (int i = 0; i < 4; i++)
                *(float4*)&f[i * 4] =
                    *(const float4*)&Af[(size_t)(m0 + ar) * 1024 + k0 + ab0 * 8 + i * 4];
            uint32_t hi[8], lo[8];
            #pragma unroll
            for (int j = 0; j < 8; j++) split2(f[2 * j], f[2 * j + 1], hi[j], lo[j]);
            int i0 = ar * 16 + ((ab0 ^ as) * 4);
            int i1 = ar * 16 + (((ab0 + 1) ^ as) * 4);
            *(uint4*)&Ah[i0] = make_uint4(hi[0], hi[1], hi[2], hi[3]);
            *(uint4*)&Ah[i1] = make_uint4(hi[4], hi[5], hi[6], hi[7]);
            *(uint4*)&Al[i0] = make_uint4(lo[0], lo[1], lo[2], lo[3]);
            *(uint4*)&Al[i1] = make_uint4(lo[4], lo[5], lo[6], lo[7]);
        }
        // ---- stage B: fp32 -> split + transpose, swizzled (R2) ----
        {
            float4 g4[4];
            #pragma unroll
            for (int j = 0; j < 4; j++)
                g4[j] = *(const float4*)&Bf[(size_t)(k0 + bk + j) * N + n0 + bc];
            #pragma unroll
            for (int nn = 0; nn < 4; nn++) {
                int n = bc + nn;
                float e0 = ((const float*)&g4[0])[nn];
                float e1 = ((const float*)&g4[1])[nn];
                float e2 = ((const float*)&g4[2])[nn];
                float e3 = ((const float*)&g4[3])[nn];
                uint32_t h0, q0, h1, q1;
                split2(e0, e1, h0, q0);
                split2(e2, e3, h1, q1);
                int bi = n * 16 + ((bb ^ swz(n)) * 4) + bp;
                *(uint2*)&Bh[bi] = make_uint2(h0, h1);
                *(uint2*)&Bl[bi] = make_uint2(q0, q1);
            }
        }
        __syncthreads();

        // ---- fragments + swapped MFMA (lane l15 = C-row) ----
        bf16x8 vbh[4], vbl[4];
        #pragma unroll
        for (int fn = 0; fn < 4; fn++) {
            int br = wn * 64 + fn * 16 + l15;
            int bi = br * 16 + ((quad ^ swz(br)) * 4);
            vbh[fn] = *(const bf16x8*)&Bh[bi];
            vbl[fn] = *(const bf16x8*)&Bl[bi];
        }
        #pragma unroll
        for (int fm = 0; fm < 4; fm++) {
            int arow = wm * 64 + fm * 16 + l15;
            int ai = arow * 16 + ((quad ^ swz(arow)) * 4);
            bf16x8 vah = *(const bf16x8*)&Ah[ai];
            bf16x8 val = *(const bf16x8*)&Al[ai];
            #pragma unroll
            for (int fn = 0; fn < 4; fn++) {
                acc[fm][fn] = __builtin_amdgcn_mfma_f32_16x16x32_bf16(vbh[fn], vah, acc[fm][fn], 0, 0, 0);
                acc[fm][fn] = __builtin_amdgcn_mfma_f32_16x16x32_bf16(vbl[fn], vah, acc[fm][fn], 0, 0, 0);
                acc[fm][fn] = __builtin_amdgcn_mfma_f32_16x16x32_bf16(vbh[fn], val, acc[fm][fn], 0, 0, 0);
            }
        }
    }

    // ---- epilogue (row-contiguous, R4-verified) ----
    #pragma unroll
    for (int fm = 0; fm < 4; fm++) {
        int row = m0 + wm * 64 + fm * 16 + l15;
        #pragma unroll
        for (int fn = 0; fn < 4; fn++) {
            int colb = n0 + wn * 64 + fn * 16 + quad * 4;
            floatx4 a = acc[fm][fn];
            if (is_qv) {
                if (colb < 1024) {
                    uint32_t h0, l0, h1, l1;
                    split2(a[0], a[1], h0, l0);
                    split2(a[2], a[3], h1, l1);
                    size_t wi = (size_t)row * 512 + (colb >> 1);
                    *(uint2*)&qh[wi] = make_uint2(h0, h1);
                    *(uint2*)&ql[wi] = make_uint2(l0, l1);
                } else {
                    uint32_t w0 = pack_bf16_rne(a[0], a[1]);
                    uint32_t w1 = pack_bf16_rne(a[2], a[3]);
                    *(uint2*)&vb[(size_t)row * 512 + ((colb - 1024) >> 1)] = make_uint2(w0, w1);
                }
            } else {
                uint32_t h0, l0, h1, l1;
                split2(a[0], a[1], h0, l0);
                split2(a[2], a[3], h1, l1);
                size_t wi = (size_t)row * 512 + (colb >> 1);
                *(uint2*)&kh[wi] = make_uint2(h0, h1);
                *(uint2*)&kl[wi] = make_uint2(l0, l1);
            }
        }
    }
}

// ---------------- proj GEMM, 128x64 tile, pre-split A ----------------------
// A: pre-split h/l [M][512 words] (R8-verified uint4+ds_write staging).
// B: fp32 [K][1024], TN=64 split+transpose (R6-verified). 512 blocks = 2/CU.
__global__ __launch_bounds__(256, 3)
void gemm_proj(const uint32_t* __restrict__ Ahg, const uint32_t* __restrict__ Alg,
               const float* __restrict__ Bf, const float* __restrict__ bias,
               float* __restrict__ Cf)
{
    __shared__ uint32_t Ah[128 * 16], Al[128 * 16], Bh[64 * 16], Bl[64 * 16];

    const int t    = threadIdx.x;
    const int lane = t & 63;
    const int w    = t >> 6;
    const int wm   = w & 1, wn = w >> 1;
    const int quad = lane >> 4, l15 = lane & 15;
    const int m0 = blockIdx.y * 128, n0 = blockIdx.x * 64;
    const int N  = 1024;

    // TN=64 B staging coords (R6)
    const int bc  = (t & 15) * 4;
    const int bk  = (t >> 4) * 2;
    const int bkw = bk >> 1;
    const int kb  = bkw >> 2, wo = bkw & 3;

    floatx4 acc[4][2];
    #pragma unroll
    for (int i = 0; i < 4; i++)
        #pragma unroll
        for (int j = 0; j < 2; j++)
            #pragma unroll
            for (int e = 0; e < 4; e++) acc[i][j][e] = 0.0f;

    for (int k0 = 0; k0 < 1024; k0 += 32) {
        if (k0) __syncthreads();
        // ---- stage A: pre-split uint4 + swizzled ds_write (R8) ----
        #pragma unroll
        for (int i = 0; i < 2; i++) {
            int idx = t + i * 256;
            int row = idx >> 2, kbl = idx & 3;
            size_t src = (size_t)(m0 + row) * 512 + (k0 >> 1) + kbl * 4;
            int dst = row * 16 + ((kbl ^ swz(row)) * 4);
            *(uint4*)&Ah[dst] = *(const uint4*)&Ahg[src];
            *(uint4*)&Al[dst] = *(const uint4*)&Alg[src];
        }
        // ---- stage B: TN=64 fp32 split+transpose (R6) ----
        {
            float4 g0 = *(const float4*)&Bf[(size_t)(k0 + bk) * N + n0 + bc];
            float4 g1 = *(const float4*)&Bf[(size_t)(k0 + bk + 1) * N + n0 + bc];
            const float* p0 = (const float*)&g0;
            const float* p1 = (const float*)&g1;
            #pragma unroll
            for (int nn = 0; nn < 4; nn++) {
                int n = bc + nn;
                uint32_t h, l;
                split2(p0[nn], p1[nn], h, l);
                int bi = n * 16 + ((kb ^ swz(n)) * 4) + wo;
                Bh[bi] = h;
                Bl[bi] = l;
            }
        }
        __syncthreads();

        bf16x8 vbh[2], vbl[2];
        #pragma unroll
        for (int fn = 0; fn < 2; fn++) {
            int br = wn * 32 + fn * 16 + l15;
            int bi = br * 16 + ((quad ^ swz(br)) * 4);
            vbh[fn] = *(const bf16x8*)&Bh[bi];
            vbl[fn] = *(const bf16x8*)&Bl[bi];
        }
        #pragma unroll
        for (int fm = 0; fm < 4; fm++) {
            int arow = wm * 64 + fm * 16 + l15;
            int ai = arow * 16 + ((quad ^ swz(arow)) * 4);
            bf16x8 vah = *(const bf16x8*)&Ah[ai];
            bf16x8 val = *(const bf16x8*)&Al[ai];
            #pragma unroll
            for (int fn = 0; fn < 2; fn++) {
                acc[fm][fn] = __builtin_amdgcn_mfma_f32_16x16x32_bf16(vbh[fn], vah, acc[fm][fn], 0, 0, 0);
                acc[fm][fn] = __builtin_amdgcn_mfma_f32_16x16x32_bf16(vbl[fn], vah, acc[fm][fn], 0, 0, 0);
                acc[fm][fn] = __builtin_amdgcn_mfma_f32_16x16x32_bf16(vbh[fn], val, acc[fm][fn], 0, 0, 0);
            }
        }
    }

    #pragma unroll
    for (int fm = 0; fm < 4; fm++) {
        int row = m0 + wm * 64 + fm * 16 + l15;
        #pragma unroll
        for (int fn = 0; fn < 2; fn++) {
            int colb = n0 + wn * 32 + fn * 16 + quad * 4;
            floatx4 a = acc[fm][fn];
            float4 bb4 = *(const float4*)&bias[colb];
            float4 v;
            v.x = a[0] + bb4.x; v.y = a[1] + bb4.y;
            v.z = a[2] + bb4.z; v.w = a[3] + bb4.w;
            *(float4*)&Cf[(size_t)row * N + colb] = v;
        }
    }
}

// ---------------- MFMA flash attention, Br=128, Bc=64 -----------------------
// R5/R8 structure; Q fragments preloaded into registers directly from global
// (no LDS transit), Qh/Ql arrays removed: LDS 43.5 KB.
#define FST 34
__global__ __launch_bounds__(256, 2)
void flash_attn(const uint32_t* __restrict__ qhg, const uint32_t* __restrict__ qlg,
                const uint32_t* __restrict__ khg, const uint32_t* __restrict__ klg,
                const uint32_t* __restrict__ vbg,
                uint32_t* __restrict__ xhg, uint32_t* __restrict__ xlg)
{
    __shared__ uint32_t Kh[64 * FST], Kl[64 * FST];
    __shared__ uint32_t Vt[64 * FST];
    __shared__ uint32_t Pt[128 * FST];

    const int t    = threadIdx.x;
    const int lane = t & 63;
    const int w    = t >> 6;
    const int quad = lane >> 4, l15 = lane & 15;
    const int qb = blockIdx.x;
    const int h  = blockIdx.y;
    const int b  = blockIdx.z;
    const float scale = 0.125f;

    const size_t rowbase = (size_t)b * SEQ;

    // ---- preload this wave's Q fragments straight from global ----
    bf16x8 vqh[2][2], vql[2][2];     // [nf][s]
    #pragma unroll
    for (int nf = 0; nf < 2; nf++)
        #pragma unroll
        for (int s = 0; s < 2; s++) {
            int qrow = w * 32 + nf * 16 + l15;
            size_t gw = (rowbase + qb * 128 + qrow) * 512 + h * 32 + s * 16 + quad * 4;
            vqh[nf][s] = *(const bf16x8*)&qhg[gw];
            vql[nf][s] = *(const bf16x8*)&qlg[gw];
        }

    float m_i[2] = {-INFINITY, -INFINITY};
    float l_i[2] = {0.0f, 0.0f};
    floatx4 acc_o[2][4];
    #pragma unroll
    for (int nf = 0; nf < 2; nf++)
        #pragma unroll
        for (int fm = 0; fm < 4; fm++)
            #pragma unroll
            for (int e = 0; e < 4; e++) acc_o[nf][fm][e] = 0.0f;

    for (int kt = 0; kt < SEQ / 64; kt++) {
        __syncthreads();
        // ---- stage K tile: 64 rows x 32 words, h+l ----
        {
            int row = t >> 2, c0 = (t & 3) * 8;
            size_t gw = (rowbase + kt * 64 + row) * 512 + h * 32 + c0;
            *(uint4*)&Kh[row * FST + c0]     = *(const uint4*)&khg[gw];
            *(uint4*)&Kh[row * FST + c0 + 4] = *(const uint4*)&khg[gw + 4];
            *(uint4*)&Kl[row * FST + c0]     = *(const uint4*)&klg[gw];
            *(uint4*)&Kl[row * FST + c0 + 4] = *(const uint4*)&klg[gw + 4];
        }
        // ---- stage V transposed: Vt[d][key] ----
        {
            int key0 = (t & 15) * 4, d0 = (t >> 4) * 4;
            uint2 v0 = *(const uint2*)&vbg[(rowbase + kt * 64 + key0 + 0) * 512 + h * 32 + (d0 >> 1)];
            uint2 v1 = *(const uint2*)&vbg[(rowbase + kt * 64 + key0 + 1) * 512 + h * 32 + (d0 >> 1)];
            uint2 v2 = *(const uint2*)&vbg[(rowbase + kt * 64 + key0 + 2) * 512 + h * 32 + (d0 >> 1)];
            uint2 v3 = *(const uint2*)&vbg[(rowbase + kt * 64 + key0 + 3) * 512 + h * 32 + (d0 >> 1)];
            uint32_t lo, hi;
            lo = (v0.x & 0xFFFFu) | (v1.x << 16);
            hi = (v2.x & 0xFFFFu) | (v3.x << 16);
            *(uint2*)&Vt[(d0 + 0) * FST + (key0 >> 1)] = make_uint2(lo, hi);
            lo = (v0.x >> 16) | (v1.x & 0xFFFF0000u);
            hi = (v2.x >> 16) | (v3.x & 0xFFFF0000u);
            *(uint2*)&Vt[(d0 + 1) * FST + (key0 >> 1)] = make_uint2(lo, hi);
            lo = (v0.y & 0xFFFFu) | (v1.y << 16);
            hi = (v2.y & 0xFFFFu) | (v3.y << 16);
            *(uint2*)&Vt[(d0 + 2) * FST + (key0 >> 1)] = make_uint2(lo, hi);
            lo = (v0.y >> 16) | (v1.y & 0xFFFF0000u);
            hi = (v2.y >> 16) | (v3.y & 0xFFFF0000u);
            *(uint2*)&Vt[(d0 + 3) * FST + (key0 >> 1)] = make_uint2(lo, hi);
        }
        __syncthreads();

        // ---- S^T = K·Q^T (bf16x3), Q from registers ----
        floatx4 sacc[2][4];
        #pragma unroll
        for (int nf = 0; nf < 2; nf++)
            #pragma unroll
            for (int fm = 0; fm < 4; fm++)
                #pragma unroll
                for (int e = 0; e < 4; e++) sacc[nf][fm][e] = 0.0f;

        #pragma unroll
        for (int s = 0; s < 2; s++) {
            #pragma unroll
            for (int fm = 0; fm < 4; fm++) {
                int ki = (fm * 16 + l15) * FST + s * 16 + quad * 4;
                bf16x8 vkh = *(const bf16x8*)&Kh[ki];
                bf16x8 vkl = *(const bf16x8*)&Kl[ki];
                #pragma unroll
                for (int nf = 0; nf < 2; nf++) {
                    sacc[nf][fm] = __builtin_amdgcn_mfma_f32_16x16x32_bf16(vkh, vqh[nf][s], sacc[nf][fm], 0, 0, 0);
                    sacc[nf][fm] = __builtin_amdgcn_mfma_f32_16x16x32_bf16(vkh, vql[nf][s], sacc[nf][fm], 0, 0, 0);
                    sacc[nf][fm] = __builtin_amdgcn_mfma_f32_16x16x32_bf16(vkl, vqh[nf][s], sacc[nf][fm], 0, 0, 0);
                }
            }
        }

        // ---- online softmax per (lane, nf) ----
        #pragma unroll
        for (int nf = 0; nf < 2; nf++) {
            float p[4][4];
            float mt = -INFINITY;
            #pragma unroll
            for (int fm = 0; fm < 4; fm++)
                #pragma unroll
                for (int r = 0; r < 4; r++) {
                    p[fm][r] = sacc[nf][fm][r] * scale;
                    mt = fmaxf(mt, p[fm][r]);
                }
            mt = fmaxf(mt, __shfl_xor(mt, 16));
            mt = fmaxf(mt, __shfl_xor(mt, 32));
            float m_new = fmaxf(m_i[nf], mt);
            float alpha = __expf(m_i[nf] - m_new);
            float rs = 0.0f;
            #pragma unroll
            for (int fm = 0; fm < 4; fm++)
                #pragma unroll
                for (int r = 0; r < 4; r++) {
                    p[fm][r] = __expf(p[fm][r] - m_new);
                    rs += p[fm][r];
                }
            rs += __shfl_xor(rs, 16);
            rs += __shfl_xor(rs, 32);
            l_i[nf] = l_i[nf] * alpha + rs;
            m_i[nf] = m_new;
            #pragma unroll
            for (int fm = 0; fm < 4; fm++)
                #pragma unroll
                for (int e = 0; e < 4; e++) acc_o[nf][fm][e] *= alpha;

            int qrow = w * 32 + nf * 16 + l15;
            #pragma unroll
            for (int fm = 0; fm < 4; fm++) {
                uint32_t u0 = pack_bf16_rne(p[fm][0], p[fm][1]);
                uint32_t u1 = pack_bf16_rne(p[fm][2], p[fm][3]);
                *(uint2*)&Pt[qrow * FST + fm * 8 + quad * 2] = make_uint2(u0, u1);
            }
        }

        // ---- O^T += Vt · P^T ----
        #pragma unroll
        for (int s = 0; s < 2; s++) {
            bf16x8 pb[2];
            #pragma unroll
            for (int nf = 0; nf < 2; nf++)
                pb[nf] = *(const bf16x8*)&Pt[(w * 32 + nf * 16 + l15) * FST + s * 16 + quad * 4];
            #pragma unroll
            for (int fm = 0; fm < 4; fm++) {
                bf16x8 va = *(const bf16x8*)&Vt[(fm * 16 + l15) * FST + s * 16 + quad * 4];
                #pragma unroll
                for (int nf = 0; nf < 2; nf++)
                    acc_o[nf][fm] = __builtin_amdgcn_mfma_f32_16x16x32_bf16(va, pb[nf], acc_o[nf][fm], 0, 0, 0);
            }
        }
    }

    // ---- epilogue: write x pre-split bf16 ----
    #pragma unroll
    for (int nf = 0; nf < 2; nf++) {
        float rl = 1.0f / l_i[nf];
        size_t row = rowbase + qb * 128 + w * 32 + nf * 16 + l15;
        #pragma unroll
        for (int fm = 0; fm < 4; fm++) {
            int d0 = fm * 16 + quad * 4;
            uint32_t h0, l0, h1, l1;
            split2(acc_o[nf][fm][0] * rl, acc_o[nf][fm][1] * rl, h0, l0);
            split2(acc_o[nf][fm][2] * rl, acc_o[nf][fm][3] * rl, h1, l1);
            size_t wi = row * 512 + ((h * 64 + d0) >> 1);
            *(uint2*)&xhg[wi] = make_uint2(h0, h1);
            *(uint2*)&xlg[wi] = make_uint2(l0, l1);
        }
    }
}

extern "C" void kernel_launch(void* const* d_in, const int* in_sizes, int n_in,
                              void* d_out, int out_size, void* d_ws, size_t ws_size,
                              hipStream_t stream)
{
    const float* input_qv = (const float*)d_in[0];
    const float* input_k  = (const float*)d_in[1];
    const float* W_qv     = (const float*)d_in[2];
    const float* W_k      = (const float*)d_in[3];
    const float* W_proj   = (const float*)d_in[4];
    const float* b_proj   = (const float*)d_in[5];
    float* out = (float*)d_out;

    const size_t RW = 4096 * 512;            // words per [4096][1024-bf16] buffer
    uint32_t* qh = (uint32_t*)d_ws;          // 5 RW = 41.9 MB total
    uint32_t* ql = qh + RW;
    uint32_t* vb = ql + RW;
    uint32_t* xh = vb + RW;
    uint32_t* xl = xh + RW;
    uint32_t* kh = (uint32_t*)d_out;         // split K parked in d_out (16.8 MB);
    uint32_t* kl = kh + RW;                  // proj GEMM rewrites out afterwards

    dim3 blk(256);
    // fused qv+k projections: 768 blocks = exactly 3/CU
    gemm_qvk<<<dim3(24, 32), blk, 0, stream>>>(
        input_qv, input_k, W_qv, W_k, qh, ql, vb, kh, kl);
    // flash attention (Q-in-registers)
    flash_attn<<<dim3(SEQ / 128, NH, BATCH), blk, 0, stream>>>(
        qh, ql, kh, kl, vb, xh, xl);
    // output projection + bias: 128x64 tiles -> 512 blocks = 2/CU
    gemm_proj<<<dim3(16, 32), blk, 0, stream>>>(
        xh, xl, W_proj, b_proj, out);
}

// Round 10
// 323.928 us; speedup vs baseline: 1.2450x; 1.0398x over previous
//
#include <hip/hip_runtime.h>
#include <stdint.h>

#define BATCH 2
#define SEQ   2048
#define DIM   1024
#define NH    16
#define DH    64

typedef short bf16x8 __attribute__((ext_vector_type(8)));
typedef float floatx4 __attribute__((ext_vector_type(4)));

__device__ __forceinline__ int swz(int r) { return (r ^ (r >> 2)) & 3; }

// Split two fp32 into packed bf16 hi-pair and lo-pair (truncation split)
__device__ __forceinline__ void split2(float x0, float x1, uint32_t& hi, uint32_t& lo) {
    uint32_t u0 = __float_as_uint(x0), u1 = __float_as_uint(x1);
    uint32_t m0 = u0 & 0xFFFF0000u;
    uint32_t m1 = u1 & 0xFFFF0000u;
    hi = (u0 >> 16) | m1;
    float l0 = x0 - __uint_as_float(m0);
    float l1 = x1 - __uint_as_float(m1);
    lo = (__float_as_uint(l0) >> 16) | (__float_as_uint(l1) & 0xFFFF0000u);
}

__device__ __forceinline__ uint32_t pack_bf16_rne(float x0, float x1) {
    uint32_t u0 = __float_as_uint(x0), u1 = __float_as_uint(x1);
    u0 += 0x7FFFu + ((u0 >> 16) & 1);
    u1 += 0x7FFFu + ((u1 >> 16) & 1);
    return (u0 >> 16) | (u1 & 0xFFFF0000u);
}

// ---------------- fused qv+k projection GEMM (R9-verified, unchanged) -------
__global__ __launch_bounds__(256, 3)
void gemm_qvk(const float* __restrict__ Aqv, const float* __restrict__ Akp,
              const float* __restrict__ Wqv, const float* __restrict__ Wkp,
              uint32_t* __restrict__ qh, uint32_t* __restrict__ ql,
              uint32_t* __restrict__ vb,
              uint32_t* __restrict__ kh, uint32_t* __restrict__ kl)
{
    __shared__ uint32_t Ah[128 * 16], Al[128 * 16], Bh[128 * 16], Bl[128 * 16];

    const int t    = threadIdx.x;
    const int lane = t & 63;
    const int w    = t >> 6;
    const int wm   = w & 1, wn = w >> 1;
    const int quad = lane >> 4, l15 = lane & 15;
    const int bx   = blockIdx.x;
    const bool is_qv = (bx < 16);
    const float* Af = is_qv ? Aqv : Akp;
    const float* Bf = is_qv ? Wqv : Wkp;
    const int N    = is_qv ? 2048 : 1024;
    const int n0   = (is_qv ? bx : bx - 16) * 128;
    const int m0   = blockIdx.y * 128;

    const int ar  = t >> 1;
    const int ab0 = (t & 1) * 2;
    const int as  = swz(ar);
    const int bc  = (t & 31) * 4;
    const int bk  = (t >> 5) * 4;
    const int bb  = bk >> 3;
    const int bp  = (bk & 7) >> 1;

    floatx4 acc[4][4];
    #pragma unroll
    for (int i = 0; i < 4; i++)
        #pragma unroll
        for (int j = 0; j < 4; j++)
            #pragma unroll
            for (int e = 0; e < 4; e++) acc[i][j][e] = 0.0f;

    for (int k0 = 0; k0 < 1024; k0 += 32) {
        if (k0) __syncthreads();
        {
            float f[16];
            #pragma unroll
            for (int i = 0; i < 4; i++)
                *(float4*)&f[i * 4] =
                    *(const float4*)&Af[(size_t)(m0 + ar) * 1024 + k0 + ab0 * 8 + i * 4];
            uint32_t hi[8], lo[8];
            #pragma unroll
            for (int j = 0; j < 8; j++) split2(f[2 * j], f[2 * j + 1], hi[j], lo[j]);
            int i0 = ar * 16 + ((ab0 ^ as) * 4);
            int i1 = ar * 16 + (((ab0 + 1) ^ as) * 4);
            *(uint4*)&Ah[i0] = make_uint4(hi[0], hi[1], hi[2], hi[3]);
            *(uint4*)&Ah[i1] = make_uint4(hi[4], hi[5], hi[6], hi[7]);
            *(uint4*)&Al[i0] = make_uint4(lo[0], lo[1], lo[2], lo[3]);
            *(uint4*)&Al[i1] = make_uint4(lo[4], lo[5], lo[6], lo[7]);
        }
        {
            float4 g4[4];
            #pragma unroll
            for (int j = 0; j < 4; j++)
                g4[j] = *(const float4*)&Bf[(size_t)(k0 + bk + j) * N + n0 + bc];
            #pragma unroll
            for (int nn = 0; nn < 4; nn++) {
                int n = bc + nn;
                float e0 = ((const float*)&g4[0])[nn];
                float e1 = ((const float*)&g4[1])[nn];
                float e2 = ((const float*)&g4[2])[nn];
                float e3 = ((const float*)&g4[3])[nn];
                uint32_t h0, q0, h1, q1;
                split2(e0, e1, h0, q0);
                split2(e2, e3, h1, q1);
                int bi = n * 16 + ((bb ^ swz(n)) * 4) + bp;
                *(uint2*)&Bh[bi] = make_uint2(h0, h1);
                *(uint2*)&Bl[bi] = make_uint2(q0, q1);
            }
        }
        __syncthreads();

        bf16x8 vbh[4], vbl[4];
        #pragma unroll
        for (int fn = 0; fn < 4; fn++) {
            int br = wn * 64 + fn * 16 + l15;
            int bi = br * 16 + ((quad ^ swz(br)) * 4);
            vbh[fn] = *(const bf16x8*)&Bh[bi];
            vbl[fn] = *(const bf16x8*)&Bl[bi];
        }
        #pragma unroll
        for (int fm = 0; fm < 4; fm++) {
            int arow = wm * 64 + fm * 16 + l15;
            int ai = arow * 16 + ((quad ^ swz(arow)) * 4);
            bf16x8 vah = *(const bf16x8*)&Ah[ai];
            bf16x8 val = *(const bf16x8*)&Al[ai];
            #pragma unroll
            for (int fn = 0; fn < 4; fn++) {
                acc[fm][fn] = __builtin_amdgcn_mfma_f32_16x16x32_bf16(vbh[fn], vah, acc[fm][fn], 0, 0, 0);
                acc[fm][fn] = __builtin_amdgcn_mfma_f32_16x16x32_bf16(vbl[fn], vah, acc[fm][fn], 0, 0, 0);
                acc[fm][fn] = __builtin_amdgcn_mfma_f32_16x16x32_bf16(vbh[fn], val, acc[fm][fn], 0, 0, 0);
            }
        }
    }

    #pragma unroll
    for (int fm = 0; fm < 4; fm++) {
        int row = m0 + wm * 64 + fm * 16 + l15;
        #pragma unroll
        for (int fn = 0; fn < 4; fn++) {
            int colb = n0 + wn * 64 + fn * 16 + quad * 4;
            floatx4 a = acc[fm][fn];
            if (is_qv) {
                if (colb < 1024) {
                    uint32_t h0, l0, h1, l1;
                    split2(a[0], a[1], h0, l0);
                    split2(a[2], a[3], h1, l1);
                    size_t wi = (size_t)row * 512 + (colb >> 1);
                    *(uint2*)&qh[wi] = make_uint2(h0, h1);
                    *(uint2*)&ql[wi] = make_uint2(l0, l1);
                } else {
                    uint32_t w0 = pack_bf16_rne(a[0], a[1]);
                    uint32_t w1 = pack_bf16_rne(a[2], a[3]);
                    *(uint2*)&vb[(size_t)row * 512 + ((colb - 1024) >> 1)] = make_uint2(w0, w1);
                }
            } else {
                uint32_t h0, l0, h1, l1;
                split2(a[0], a[1], h0, l0);
                split2(a[2], a[3], h1, l1);
                size_t wi = (size_t)row * 512 + (colb >> 1);
                *(uint2*)&kh[wi] = make_uint2(h0, h1);
                *(uint2*)&kl[wi] = make_uint2(l0, l1);
            }
        }
    }
}

// ---------------- proj GEMM, 128x64 tile (R9-verified, unchanged) -----------
__global__ __launch_bounds__(256, 3)
void gemm_proj(const uint32_t* __restrict__ Ahg, const uint32_t* __restrict__ Alg,
               const float* __restrict__ Bf, const float* __restrict__ bias,
               float* __restrict__ Cf)
{
    __shared__ uint32_t Ah[128 * 16], Al[128 * 16], Bh[64 * 16], Bl[64 * 16];

    const int t    = threadIdx.x;
    const int lane = t & 63;
    const int w    = t >> 6;
    const int wm   = w & 1, wn = w >> 1;
    const int quad = lane >> 4, l15 = lane & 15;
    const int m0 = blockIdx.y * 128, n0 = blockIdx.x * 64;
    const int N  = 1024;

    const int bc  = (t & 15) * 4;
    const int bk  = (t >> 4) * 2;
    const int bkw = bk >> 1;
    const int kb  = bkw >> 2, wo = bkw & 3;

    floatx4 acc[4][2];
    #pragma unroll
    for (int i = 0; i < 4; i++)
        #pragma unroll
        for (int j = 0; j < 2; j++)
            #pragma unroll
            for (int e = 0; e < 4; e++) acc[i][j][e] = 0.0f;

    for (int k0 = 0; k0 < 1024; k0 += 32) {
        if (k0) __syncthreads();
        #pragma unroll
        for (int i = 0; i < 2; i++) {
            int idx = t + i * 256;
            int row = idx >> 2, kbl = idx & 3;
            size_t src = (size_t)(m0 + row) * 512 + (k0 >> 1) + kbl * 4;
            int dst = row * 16 + ((kbl ^ swz(row)) * 4);
            *(uint4*)&Ah[dst] = *(const uint4*)&Ahg[src];
            *(uint4*)&Al[dst] = *(const uint4*)&Alg[src];
        }
        {
            float4 g0 = *(const float4*)&Bf[(size_t)(k0 + bk) * N + n0 + bc];
            float4 g1 = *(const float4*)&Bf[(size_t)(k0 + bk + 1) * N + n0 + bc];
            const float* p0 = (const float*)&g0;
            const float* p1 = (const float*)&g1;
            #pragma unroll
            for (int nn = 0; nn < 4; nn++) {
                int n = bc + nn;
                uint32_t h, l;
                split2(p0[nn], p1[nn], h, l);
                int bi = n * 16 + ((kb ^ swz(n)) * 4) + wo;
                Bh[bi] = h;
                Bl[bi] = l;
            }
        }
        __syncthreads();

        bf16x8 vbh[2], vbl[2];
        #pragma unroll
        for (int fn = 0; fn < 2; fn++) {
            int br = wn * 32 + fn * 16 + l15;
            int bi = br * 16 + ((quad ^ swz(br)) * 4);
            vbh[fn] = *(const bf16x8*)&Bh[bi];
            vbl[fn] = *(const bf16x8*)&Bl[bi];
        }
        #pragma unroll
        for (int fm = 0; fm < 4; fm++) {
            int arow = wm * 64 + fm * 16 + l15;
            int ai = arow * 16 + ((quad ^ swz(arow)) * 4);
            bf16x8 vah = *(const bf16x8*)&Ah[ai];
            bf16x8 val = *(const bf16x8*)&Al[ai];
            #pragma unroll
            for (int fn = 0; fn < 2; fn++) {
                acc[fm][fn] = __builtin_amdgcn_mfma_f32_16x16x32_bf16(vbh[fn], vah, acc[fm][fn], 0, 0, 0);
                acc[fm][fn] = __builtin_amdgcn_mfma_f32_16x16x32_bf16(vbl[fn], vah, acc[fm][fn], 0, 0, 0);
                acc[fm][fn] = __builtin_amdgcn_mfma_f32_16x16x32_bf16(vbh[fn], val, acc[fm][fn], 0, 0, 0);
            }
        }
    }

    #pragma unroll
    for (int fm = 0; fm < 4; fm++) {
        int row = m0 + wm * 64 + fm * 16 + l15;
        #pragma unroll
        for (int fn = 0; fn < 2; fn++) {
            int colb = n0 + wn * 32 + fn * 16 + quad * 4;
            floatx4 a = acc[fm][fn];
            float4 bb4 = *(const float4*)&bias[colb];
            float4 v;
            v.x = a[0] + bb4.x; v.y = a[1] + bb4.y;
            v.z = a[2] + bb4.z; v.w = a[3] + bb4.w;
            *(float4*)&Cf[(size_t)row * N + colb] = v;
        }
    }
}

// ---------------- MFMA flash attention, Br=128, Bc=64 -----------------------
// R5 structure (Q in LDS — register-Q regressed twice) + K/V register
// prefetch: global loads for tile kt+1 issue right after the compute barrier,
// so they complete during compute; loop-top staging is pure ds_write.
#define FST 34
__global__ __launch_bounds__(256, 2)
void flash_attn(const uint32_t* __restrict__ qhg, const uint32_t* __restrict__ qlg,
                const uint32_t* __restrict__ khg, const uint32_t* __restrict__ klg,
                const uint32_t* __restrict__ vbg,
                uint32_t* __restrict__ xhg, uint32_t* __restrict__ xlg)
{
    __shared__ uint32_t Qh[128 * FST], Ql[128 * FST];
    __shared__ uint32_t Kh[64 * FST],  Kl[64 * FST];
    __shared__ uint32_t Vt[64 * FST];
    __shared__ uint32_t Pt[128 * FST];

    const int t    = threadIdx.x;
    const int lane = t & 63;
    const int w    = t >> 6;
    const int quad = lane >> 4, l15 = lane & 15;
    const int qb = blockIdx.x;
    const int h  = blockIdx.y;
    const int b  = blockIdx.z;
    const float scale = 0.125f;

    const size_t rowbase = (size_t)b * SEQ;

    // ---- stage Q tile once: 128 rows x 32 words, h+l ----
    {
        int row = t >> 1, c0 = (t & 1) * 16;
        size_t gw = (rowbase + qb * 128 + row) * 512 + h * 32 + c0;
        #pragma unroll
        for (int j = 0; j < 4; j++) {
            *(uint4*)&Qh[row * FST + c0 + j * 4] = *(const uint4*)&qhg[gw + j * 4];
            *(uint4*)&Ql[row * FST + c0 + j * 4] = *(const uint4*)&qlg[gw + j * 4];
        }
    }

    // ---- prefetch coords + prefetch tile kt=0 into registers ----
    const int krow = t >> 2, kc0 = (t & 3) * 8;          // K: row, word base
    const int vkey0 = (t & 15) * 4, vd0 = (t >> 4) * 4;  // V: 4 rows, 4 d
    uint4 pkh0, pkh1, pkl0, pkl1;
    uint2 pv0, pv1, pv2, pv3;
    {
        size_t gw = (rowbase + krow) * 512 + h * 32 + kc0;
        pkh0 = *(const uint4*)&khg[gw];
        pkh1 = *(const uint4*)&khg[gw + 4];
        pkl0 = *(const uint4*)&klg[gw];
        pkl1 = *(const uint4*)&klg[gw + 4];
        size_t vw = (rowbase + vkey0) * 512 + h * 32 + (vd0 >> 1);
        pv0 = *(const uint2*)&vbg[vw];
        pv1 = *(const uint2*)&vbg[vw + 512];
        pv2 = *(const uint2*)&vbg[vw + 1024];
        pv3 = *(const uint2*)&vbg[vw + 1536];
    }

    float m_i[2] = {-INFINITY, -INFINITY};
    float l_i[2] = {0.0f, 0.0f};
    floatx4 acc_o[2][4];
    #pragma unroll
    for (int nf = 0; nf < 2; nf++)
        #pragma unroll
        for (int fm = 0; fm < 4; fm++)
            #pragma unroll
            for (int e = 0; e < 4; e++) acc_o[nf][fm][e] = 0.0f;

    for (int kt = 0; kt < SEQ / 64; kt++) {
        __syncthreads();   // prev iter's readers done with Kh/Kl/Vt (also orders Q staging)
        // ---- stage K from registers ----
        *(uint4*)&Kh[krow * FST + kc0]     = pkh0;
        *(uint4*)&Kh[krow * FST + kc0 + 4] = pkh1;
        *(uint4*)&Kl[krow * FST + kc0]     = pkl0;
        *(uint4*)&Kl[krow * FST + kc0 + 4] = pkl1;
        // ---- stage V transposed from registers ----
        {
            uint32_t lo, hi;
            lo = (pv0.x & 0xFFFFu) | (pv1.x << 16);
            hi = (pv2.x & 0xFFFFu) | (pv3.x << 16);
            *(uint2*)&Vt[(vd0 + 0) * FST + (vkey0 >> 1)] = make_uint2(lo, hi);
            lo = (pv0.x >> 16) | (pv1.x & 0xFFFF0000u);
            hi = (pv2.x >> 16) | (pv3.x & 0xFFFF0000u);
            *(uint2*)&Vt[(vd0 + 1) * FST + (vkey0 >> 1)] = make_uint2(lo, hi);
            lo = (pv0.y & 0xFFFFu) | (pv1.y << 16);
            hi = (pv2.y & 0xFFFFu) | (pv3.y << 16);
            *(uint2*)&Vt[(vd0 + 2) * FST + (vkey0 >> 1)] = make_uint2(lo, hi);
            lo = (pv0.y >> 16) | (pv1.y & 0xFFFF0000u);
            hi = (pv2.y >> 16) | (pv3.y & 0xFFFF0000u);
            *(uint2*)&Vt[(vd0 + 3) * FST + (vkey0 >> 1)] = make_uint2(lo, hi);
        }
        __syncthreads();

        // ---- prefetch tile kt+1 (completes during compute below) ----
        if (kt + 1 < SEQ / 64) {
            size_t gw = (rowbase + (kt + 1) * 64 + krow) * 512 + h * 32 + kc0;
            pkh0 = *(const uint4*)&khg[gw];
            pkh1 = *(const uint4*)&khg[gw + 4];
            pkl0 = *(const uint4*)&klg[gw];
            pkl1 = *(const uint4*)&klg[gw + 4];
            size_t vw = (rowbase + (kt + 1) * 64 + vkey0) * 512 + h * 32 + (vd0 >> 1);
            pv0 = *(const uint2*)&vbg[vw];
            pv1 = *(const uint2*)&vbg[vw + 512];
            pv2 = *(const uint2*)&vbg[vw + 1024];
            pv3 = *(const uint2*)&vbg[vw + 1536];
        }

        // ---- S^T = K·Q^T (bf16x3), 2 n-frags per wave ----
        floatx4 sacc[2][4];
        #pragma unroll
        for (int nf = 0; nf < 2; nf++)
            #pragma unroll
            for (int fm = 0; fm < 4; fm++)
                #pragma unroll
                for (int e = 0; e < 4; e++) sacc[nf][fm][e] = 0.0f;

        #pragma unroll
        for (int s = 0; s < 2; s++) {
            bf16x8 vqh[2], vql[2];
            #pragma unroll
            for (int nf = 0; nf < 2; nf++) {
                int qi = (w * 32 + nf * 16 + l15) * FST + s * 16 + quad * 4;
                vqh[nf] = *(const bf16x8*)&Qh[qi];
                vql[nf] = *(const bf16x8*)&Ql[qi];
            }
            #pragma unroll
            for (int fm = 0; fm < 4; fm++) {
                int ki = (fm * 16 + l15) * FST + s * 16 + quad * 4;
                bf16x8 vkh = *(const bf16x8*)&Kh[ki];
                bf16x8 vkl = *(const bf16x8*)&Kl[ki];
                #pragma unroll
                for (int nf = 0; nf < 2; nf++) {
                    sacc[nf][fm] = __builtin_amdgcn_mfma_f32_16x16x32_bf16(vkh, vqh[nf], sacc[nf][fm], 0, 0, 0);
                    sacc[nf][fm] = __builtin_amdgcn_mfma_f32_16x16x32_bf16(vkh, vql[nf], sacc[nf][fm], 0, 0, 0);
                    sacc[nf][fm] = __builtin_amdgcn_mfma_f32_16x16x32_bf16(vkl, vqh[nf], sacc[nf][fm], 0, 0, 0);
                }
            }
        }

        // ---- online softmax per (lane, nf) ----
        #pragma unroll
        for (int nf = 0; nf < 2; nf++) {
            float p[4][4];
            float mt = -INFINITY;
            #pragma unroll
            for (int fm = 0; fm < 4; fm++)
                #pragma unroll
                for (int r = 0; r < 4; r++) {
                    p[fm][r] = sacc[nf][fm][r] * scale;
                    mt = fmaxf(mt, p[fm][r]);
                }
            mt = fmaxf(mt, __shfl_xor(mt, 16));
            mt = fmaxf(mt, __shfl_xor(mt, 32));
            float m_new = fmaxf(m_i[nf], mt);
            float alpha = __expf(m_i[nf] - m_new);
            float rs = 0.0f;
            #pragma unroll
            for (int fm = 0; fm < 4; fm++)
                #pragma unroll
                for (int r = 0; r < 4; r++) {
                    p[fm][r] = __expf(p[fm][r] - m_new);
                    rs += p[fm][r];
                }
            rs += __shfl_xor(rs, 16);
            rs += __shfl_xor(rs, 32);
            l_i[nf] = l_i[nf] * alpha + rs;
            m_i[nf] = m_new;
            #pragma unroll
            for (int fm = 0; fm < 4; fm++)
                #pragma unroll
                for (int e = 0; e < 4; e++) acc_o[nf][fm][e] *= alpha;

            int qrow = w * 32 + nf * 16 + l15;
            #pragma unroll
            for (int fm = 0; fm < 4; fm++) {
                uint32_t u0 = pack_bf16_rne(p[fm][0], p[fm][1]);
                uint32_t u1 = pack_bf16_rne(p[fm][2], p[fm][3]);
                *(uint2*)&Pt[qrow * FST + fm * 8 + quad * 2] = make_uint2(u0, u1);
            }
        }

        // ---- O^T += Vt · P^T ----
        #pragma unroll
        for (int s = 0; s < 2; s++) {
            bf16x8 pb[2];
            #pragma unroll
            for (int nf = 0; nf < 2; nf++)
                pb[nf] = *(const bf16x8*)&Pt[(w * 32 + nf * 16 + l15) * FST + s * 16 + quad * 4];
            #pragma unroll
            for (int fm = 0; fm < 4; fm++) {
                bf16x8 va = *(const bf16x8*)&Vt[(fm * 16 + l15) * FST + s * 16 + quad * 4];
                #pragma unroll
                for (int nf = 0; nf < 2; nf++)
                    acc_o[nf][fm] = __builtin_amdgcn_mfma_f32_16x16x32_bf16(va, pb[nf], acc_o[nf][fm], 0, 0, 0);
            }
        }
    }

    // ---- epilogue: write x pre-split bf16 ----
    #pragma unroll
    for (int nf = 0; nf < 2; nf++) {
        float rl = 1.0f / l_i[nf];
        size_t row = rowbase + qb * 128 + w * 32 + nf * 16 + l15;
        #pragma unroll
        for (int fm = 0; fm < 4; fm++) {
            int d0 = fm * 16 + quad * 4;
            uint32_t h0, l0, h1, l1;
            split2(acc_o[nf][fm][0] * rl, acc_o[nf][fm][1] * rl, h0, l0);
            split2(acc_o[nf][fm][2] * rl, acc_o[nf][fm][3] * rl, h1, l1);
            size_t wi = row * 512 + ((h * 64 + d0) >> 1);
            *(uint2*)&xhg[wi] = make_uint2(h0, h1);
            *(uint2*)&xlg[wi] = make_uint2(l0, l1);
        }
    }
}

extern "C" void kernel_launch(void* const* d_in, const int* in_sizes, int n_in,
                              void* d_out, int out_size, void* d_ws, size_t ws_size,
                              hipStream_t stream)
{
    const float* input_qv = (const float*)d_in[0];
    const float* input_k  = (const float*)d_in[1];
    const float* W_qv     = (const float*)d_in[2];
    const float* W_k      = (const float*)d_in[3];
    const float* W_proj   = (const float*)d_in[4];
    const float* b_proj   = (const float*)d_in[5];
    float* out = (float*)d_out;

    const size_t RW = 4096 * 512;            // words per [4096][1024-bf16] buffer
    uint32_t* qh = (uint32_t*)d_ws;          // 5 RW = 41.9 MB total
    uint32_t* ql = qh + RW;
    uint32_t* vb = ql + RW;
    uint32_t* xh = vb + RW;
    uint32_t* xl = xh + RW;
    uint32_t* kh = (uint32_t*)d_out;         // split K parked in d_out (16.8 MB);
    uint32_t* kl = kh + RW;                  // proj GEMM rewrites out afterwards

    dim3 blk(256);
    // fused qv+k projections: 768 blocks = exactly 3/CU
    gemm_qvk<<<dim3(24, 32), blk, 0, stream>>>(
        input_qv, input_k, W_qv, W_k, qh, ql, vb, kh, kl);
    // flash attention (Q in LDS + K/V register prefetch)
    flash_attn<<<dim3(SEQ / 128, NH, BATCH), blk, 0, stream>>>(
        qh, ql, kh, kl, vb, xh, xl);
    // output projection + bias: 128x64 tiles -> 512 blocks = 2/CU
    gemm_proj<<<dim3(16, 32), blk, 0, stream>>>(
        xh, xl, W_proj, b_proj, out);
}